// Round 3
// baseline (1488.281 us; speedup 1.0000x reference)
//
#include <hip/hip_runtime.h>
#include <math.h>

#define NPTS 4096
#define DIM 64
#define LOGW (-8.317766166719343f)   // -log(4096)
#define NEGINF (-__builtin_inff())

typedef __bf16 bf16x8 __attribute__((ext_vector_type(8)));
typedef float f32x4 __attribute__((ext_vector_type(4)));

static __device__ __forceinline__ f32x4 mfma16(bf16x8 a, bf16x8 b, f32x4 c) {
  return __builtin_amdgcn_mfma_f32_16x16x32_bf16(a, b, c, 0, 0, 0);
}

// ---------------------------------------------------------------------------
// Normalize rows to unit L2 norm and split into bf16 hi/lo pairs
// (v = hi + lo, |lo| <= 2^-9 |v| -> split-bf16 GEMM ~ fp32 accuracy).
// ---------------------------------------------------------------------------
__global__ __launch_bounds__(256) void norm_split_kernel(
    const float* __restrict__ x, const float* __restrict__ y,
    __bf16* __restrict__ xh, __bf16* __restrict__ xl,
    __bf16* __restrict__ yh, __bf16* __restrict__ yl) {
  int row  = blockIdx.x * 4 + (threadIdx.x >> 6);
  int lane = threadIdx.x & 63;
  const float* src; __bf16 *dh, *dl;
  if (row < NPTS) {
    src = x + (size_t)row * DIM; dh = xh + (size_t)row * DIM; dl = xl + (size_t)row * DIM;
  } else {
    int r = row - NPTS;
    src = y + (size_t)r * DIM; dh = yh + (size_t)r * DIM; dl = yl + (size_t)r * DIM;
  }
  float v = src[lane];
  float s = v * v;
  #pragma unroll
  for (int o = 32; o; o >>= 1) s += __shfl_xor(s, o, 64);
  v *= 1.0f / sqrtf(s);
  __bf16 h = (__bf16)v;
  __bf16 l = (__bf16)(v - (float)h);
  dh[lane] = h;
  dl[lane] = l;
}

// ---------------------------------------------------------------------------
// Fused pass: recompute C tiles via split-bf16 MFMA and do the online
// row-logsumexp directly on the fp32 accumulators. No C matrix in memory.
//   mat 0: C(x,y) rows, h from pot[1] (g_ab)  -> partials for ft_ba
//   mat 1: C(y,x) rows, h from pot[0] (f_ba)  -> partials for gt_ab
//   mat 2: C(x,x) rows, h from pot[2] (f_aa)  -> partials for ft_aa
//   mat 3: C(y,y) rows, h from pot[3] (g_bb)  -> partials for gt_bb
// t = h[col] - (1 - dot)/eps = fma(dot, inv_eps, h[col] - inv_eps)  (clamp of
// C at 0 dropped: |C<0| <= 4e-6 rounding, effect ~1e-6 on the loss).
// Wave: 32 rows (2 MFMA strips) x 512 cols (32 col-tiles of 16).
// Block: 4 waves = 128 rows x 512 cols (waves share B -> L1 reuse).
// Grid: (colgrp 8, rowgrp 32, mat 4) = 1024 blocks.
// Partials (m, s) per (row, colgrp) merged by merge_kernel.
// ---------------------------------------------------------------------------
__global__ __launch_bounds__(256) void pass_kernel(
    const __bf16* __restrict__ xh, const __bf16* __restrict__ xl,
    const __bf16* __restrict__ yh, const __bf16* __restrict__ yl,
    const float* __restrict__ potOld, float2* __restrict__ part,
    float inv_eps, int use_pot) {
  int mat = blockIdx.z;
  const __bf16 *Ah, *Al, *Bh, *Bl;
  if (mat == 0)      { Ah = xh; Al = xl; Bh = yh; Bl = yl; }
  else if (mat == 1) { Ah = yh; Al = yl; Bh = xh; Bl = xl; }
  else if (mat == 2) { Ah = xh; Al = xl; Bh = xh; Bl = xl; }
  else               { Ah = yh; Al = yl; Bh = yh; Bl = yl; }
  int ridx = (mat == 0) ? 1 : ((mat == 1) ? 0 : mat);

  int colbase = blockIdx.x * 512;
  // stage h' = pot[col]/eps + LOGW - 1/eps into LDS
  __shared__ float hp[512];
  {
    int t0 = threadIdx.x;
    #pragma unroll
    for (int e = 0; e < 2; ++e) {
      int jj = t0 + e * 256;
      float p = use_pot ? potOld[(size_t)ridx * NPTS + colbase + jj] : 0.0f;
      hp[jj] = fmaf(p, inv_eps, LOGW) - inv_eps;
    }
  }
  __syncthreads();

  int wave = threadIdx.x >> 6, L = threadIdx.x & 63;
  int mrow = L & 15, quad = L >> 4;
  int row0 = blockIdx.y * 128 + wave * 32;

  // A fragments for 2 strips of 16 rows
  bf16x8 a_h[2][2], a_l[2][2];
  #pragma unroll
  for (int s = 0; s < 2; ++s) {
    size_t ab = (size_t)(row0 + s * 16 + mrow) * DIM + quad * 8;
    a_h[s][0] = *(const bf16x8*)(Ah + ab);
    a_h[s][1] = *(const bf16x8*)(Ah + ab + 32);
    a_l[s][0] = *(const bf16x8*)(Al + ab);
    a_l[s][1] = *(const bf16x8*)(Al + ab + 32);
  }

  float m[2][4], sm[2][4];
  #pragma unroll
  for (int s = 0; s < 2; ++s)
    #pragma unroll
    for (int q = 0; q < 4; ++q) { m[s][q] = NEGINF; sm[s][q] = 0.0f; }

  #pragma unroll 2
  for (int ct = 0; ct < 32; ++ct) {
    size_t bb = (size_t)(colbase + ct * 16 + mrow) * DIM + quad * 8;
    bf16x8 bh0 = *(const bf16x8*)(Bh + bb);
    bf16x8 bh1 = *(const bf16x8*)(Bh + bb + 32);
    bf16x8 bl0 = *(const bf16x8*)(Bl + bb);
    bf16x8 bl1 = *(const bf16x8*)(Bl + bb + 32);
    float hpv = hp[ct * 16 + mrow];
    #pragma unroll
    for (int s = 0; s < 2; ++s) {
      f32x4 acc = {0.0f, 0.0f, 0.0f, 0.0f};
      acc = mfma16(a_h[s][0], bh0, acc);
      acc = mfma16(a_h[s][1], bh1, acc);
      acc = mfma16(a_l[s][0], bh0, acc);
      acc = mfma16(a_l[s][1], bh1, acc);
      acc = mfma16(a_h[s][0], bl0, acc);
      acc = mfma16(a_h[s][1], bl1, acc);
      #pragma unroll
      for (int q = 0; q < 4; ++q) {
        float t = fmaf(acc[q], inv_eps, hpv);
        float mn = fmaxf(m[s][q], t);
        sm[s][q] = fmaf(sm[s][q], __expf(m[s][q] - mn), __expf(t - mn));
        m[s][q] = mn;
      }
    }
  }

  // merge (m, s) across the 16 lanes of each quad group (cols)
  #pragma unroll
  for (int o = 1; o < 16; o <<= 1) {
    #pragma unroll
    for (int s = 0; s < 2; ++s)
      #pragma unroll
      for (int q = 0; q < 4; ++q) {
        float m2 = __shfl_xor(m[s][q], o, 64);
        float s2 = __shfl_xor(sm[s][q], o, 64);
        float mn = fmaxf(m[s][q], m2);
        sm[s][q] = sm[s][q] * __expf(m[s][q] - mn) + s2 * __expf(m2 - mn);
        m[s][q] = mn;
      }
  }
  if (mrow == 0) {
    #pragma unroll
    for (int s = 0; s < 2; ++s)
      #pragma unroll
      for (int q = 0; q < 4; ++q) {
        int row = row0 + s * 16 + quad * 4 + q;
        part[((size_t)mat * NPTS + row) * 8 + blockIdx.x] =
            make_float2(m[s][q], sm[s][q]);
      }
  }
}

// ---------------------------------------------------------------------------
// Merge the 8 column-chunk partials per row -> softmin value, then apply the
// potential update (avg=1: 0.5*(old+new); avg=0: assign).
// Grid 64 x 256 covers all 4*4096 rows.
// ---------------------------------------------------------------------------
__global__ __launch_bounds__(256) void merge_kernel(
    const float2* __restrict__ part,
    const float* __restrict__ potOld, float* __restrict__ potNew,
    float eps, int avg) {
  int r = blockIdx.x * 256 + threadIdx.x;   // 0 .. 4*NPTS-1
  float m = NEGINF, s = 0.0f;
  #pragma unroll
  for (int c = 0; c < 8; ++c) {
    float2 p = part[(size_t)r * 8 + c];
    float mn = fmaxf(m, p.x);
    s = s * __expf(m - mn) + p.y * __expf(p.x - mn);
    m = mn;
  }
  float ft = -eps * (m + __logf(s));
  potNew[r] = avg ? 0.5f * (potOld[r] + ft) : ft;
}

// ---------------------------------------------------------------------------
// out = mean(f_ba - f_aa) + mean(g_ab - g_bb); pot layout [4][NPTS]
// ---------------------------------------------------------------------------
__global__ __launch_bounds__(256) void final_kernel(
    const float* __restrict__ pot, float* __restrict__ out) {
  __shared__ float red[256];
  float s = 0.0f;
  for (int j = threadIdx.x; j < NPTS; j += 256)
    s += (pot[j] - pot[2 * NPTS + j]) + (pot[NPTS + j] - pot[3 * NPTS + j]);
  red[threadIdx.x] = s;
  __syncthreads();
  #pragma unroll
  for (int o = 128; o; o >>= 1) {
    if (threadIdx.x < o) red[threadIdx.x] += red[threadIdx.x + o];
    __syncthreads();
  }
  if (threadIdx.x == 0) out[0] = red[0] / (float)NPTS;
}

extern "C" void kernel_launch(void* const* d_in, const int* in_sizes, int n_in,
                              void* d_out, int out_size, void* d_ws, size_t ws_size,
                              hipStream_t stream) {
  const float* x = (const float*)d_in[0];
  const float* y = (const float*)d_in[1];
  char* ws = (char*)d_ws;

  // workspace layout (tiny now: ~3.2 MB)
  __bf16* xh = (__bf16*)ws;
  __bf16* xl = xh + (size_t)NPTS * DIM;
  __bf16* yh = xl + (size_t)NPTS * DIM;
  __bf16* yl = yh + (size_t)NPTS * DIM;
  float* potA = (float*)(yl + (size_t)NPTS * DIM);
  float* potB = potA + 4 * (size_t)NPTS;
  float2* part = (float2*)(potB + 4 * (size_t)NPTS);
  size_t needed = (size_t)((char*)(part + 4 * (size_t)NPTS * 8) - ws);
  if (ws_size < needed) return;

  norm_split_kernel<<<2048, 256, 0, stream>>>(x, y, xh, xl, yh, yl);

  // geomloss epsilon schedule (p=2, blur=0.05, scaling=0.8, diameter=2)
  double lst[32];
  int c = 0;
  lst[c++] = 4.0;
  double start = 2.0 * log(2.0), stop = 2.0 * log(0.05), step = 2.0 * log(0.8);
  for (int k = 0;; ++k) {
    double v = start + (double)k * step;
    if (v <= stop) break;
    lst[c++] = exp(v);
  }
  lst[c++] = 0.05 * 0.05;   // c == 19

  // sweeps: p=0 init (no pot, assign); p=1..c loop (avg); p=c+1 final (assign)
  for (int p = 0; p < c + 2; ++p) {
    double e = (p == 0) ? lst[0] : ((p <= c) ? lst[p - 1] : lst[c - 1]);
    float eps = (float)e;
    float inv_eps = 1.0f / eps;
    int use_pot = (p > 0) ? 1 : 0;
    int avg = (p >= 1 && p <= c) ? 1 : 0;
    const float* po = (p & 1) ? potB : potA;
    float* pn       = (p & 1) ? potA : potB;
    pass_kernel<<<dim3(8, 32, 4), 256, 0, stream>>>(
        xh, xl, yh, yl, po, part, inv_eps, use_pot);
    merge_kernel<<<64, 256, 0, stream>>>(part, po, pn, eps, avg);
  }
  // 21 sweeps; last sweep (p=20, even) wrote potB
  final_kernel<<<1, 256, 0, stream>>>(potB, (float*)d_out);
}

// Round 4
// 1480.885 us; speedup vs baseline: 1.0050x; 1.0050x over previous
//
#include <hip/hip_runtime.h>
#include <math.h>

#define NPTS 4096
#define DIM 64
#define LOGW (-8.317766166719343f)   // -log(4096)
#define NEGINF (-__builtin_inff())
#define LOG2E 1.4426950408889634f
#define LN2 0.6931471805599453f

typedef __bf16 bf16x8 __attribute__((ext_vector_type(8)));
typedef float f32x4 __attribute__((ext_vector_type(4)));

static __device__ __forceinline__ f32x4 mfma16(bf16x8 a, bf16x8 b, f32x4 c) {
  return __builtin_amdgcn_mfma_f32_16x16x32_bf16(a, b, c, 0, 0, 0);
}

// ---------------------------------------------------------------------------
// Normalize rows to unit L2 norm and split into bf16 hi/lo pairs
// (v = hi + lo, |lo| <= 2^-9 |v| -> split-bf16 GEMM ~ fp32 accuracy).
// ---------------------------------------------------------------------------
__global__ __launch_bounds__(256) void norm_split_kernel(
    const float* __restrict__ x, const float* __restrict__ y,
    __bf16* __restrict__ xh, __bf16* __restrict__ xl,
    __bf16* __restrict__ yh, __bf16* __restrict__ yl) {
  int row  = blockIdx.x * 4 + (threadIdx.x >> 6);
  int lane = threadIdx.x & 63;
  const float* src; __bf16 *dh, *dl;
  if (row < NPTS) {
    src = x + (size_t)row * DIM; dh = xh + (size_t)row * DIM; dl = xl + (size_t)row * DIM;
  } else {
    int r = row - NPTS;
    src = y + (size_t)r * DIM; dh = yh + (size_t)r * DIM; dl = yl + (size_t)r * DIM;
  }
  float v = src[lane];
  float s = v * v;
  #pragma unroll
  for (int o = 32; o; o >>= 1) s += __shfl_xor(s, o, 64);
  v *= 1.0f / sqrtf(s);
  __bf16 h = (__bf16)v;
  __bf16 l = (__bf16)(v - (float)h);
  dh[lane] = h;
  dl[lane] = l;
}

// ---------------------------------------------------------------------------
// Fused pass, two-phase super-tiles, exp2 domain.
//   t2 = log2e * (LOGW + pot[col]/eps - (1 - dot)/eps)
//      = fma(dot_acc, k1, hp2[col]),  k1 = inv_eps*log2e,
//        hp2[col] = fma(pot[col], k1, k0), k0 = (LOGW - inv_eps)*log2e.
// Wave: 32 rows (2 strips) x 512 cols; super-tile = 4 col-tiles (64 cols):
//   phase A: 48 MFMAs -> acc[4][2] (f32x4), phase B: in-register transform,
//   4-deep local max, ONE (m,s) rescale per super-tile, independent exp2s.
// Block: 4 waves = 128 rows. Grid (8 colgrp, 32 rowgrp, 4 mats) = 1024 blocks
// -> 16 waves/CU fully resident at <=128 VGPR (__launch_bounds__(256,4)).
// Partials (m2, s) per (row, colgrp) -> merge_kernel.
// ---------------------------------------------------------------------------
__global__ __launch_bounds__(256, 4) void pass_kernel(
    const __bf16* __restrict__ xh, const __bf16* __restrict__ xl,
    const __bf16* __restrict__ yh, const __bf16* __restrict__ yl,
    const float* __restrict__ potOld, float2* __restrict__ part,
    float k1, float k0, int use_pot) {
  int mat = blockIdx.z;
  const __bf16 *Ah, *Al, *Bh, *Bl;
  if (mat == 0)      { Ah = xh; Al = xl; Bh = yh; Bl = yl; }
  else if (mat == 1) { Ah = yh; Al = yl; Bh = xh; Bl = xl; }
  else if (mat == 2) { Ah = xh; Al = xl; Bh = xh; Bl = xl; }
  else               { Ah = yh; Al = yl; Bh = yh; Bl = yl; }
  int ridx = (mat == 0) ? 1 : ((mat == 1) ? 0 : mat);

  int colbase = blockIdx.x * 512;
  __shared__ float hp2[512];
  #pragma unroll
  for (int e = 0; e < 2; ++e) {
    int jj = threadIdx.x + e * 256;
    float p = use_pot ? potOld[(size_t)ridx * NPTS + colbase + jj] : 0.0f;
    hp2[jj] = fmaf(p, k1, k0);
  }
  __syncthreads();

  int wave = threadIdx.x >> 6, L = threadIdx.x & 63;
  int mrow = L & 15, quad = L >> 4;
  int row0 = blockIdx.y * 128 + wave * 32;

  bf16x8 a_h[2][2], a_l[2][2];
  #pragma unroll
  for (int s = 0; s < 2; ++s) {
    size_t ab = (size_t)(row0 + s * 16 + mrow) * DIM + quad * 8;
    a_h[s][0] = *(const bf16x8*)(Ah + ab);
    a_h[s][1] = *(const bf16x8*)(Ah + ab + 32);
    a_l[s][0] = *(const bf16x8*)(Al + ab);
    a_l[s][1] = *(const bf16x8*)(Al + ab + 32);
  }

  float m[2][4], sm[2][4];
  #pragma unroll
  for (int s = 0; s < 2; ++s)
    #pragma unroll
    for (int q = 0; q < 4; ++q) { m[s][q] = NEGINF; sm[s][q] = 0.0f; }

  for (int st = 0; st < 8; ++st) {
    // ---- phase A: MFMA block (4 col-tiles x 2 strips x 6 MFMA) ----
    f32x4 acc[4][2];
    #pragma unroll
    for (int c4 = 0; c4 < 4; ++c4)
      #pragma unroll
      for (int s = 0; s < 2; ++s) acc[c4][s] = (f32x4){0.f, 0.f, 0.f, 0.f};
    #pragma unroll
    for (int c4 = 0; c4 < 4; ++c4) {
      int ct = st * 4 + c4;
      size_t bb = (size_t)(colbase + ct * 16 + mrow) * DIM + quad * 8;
      bf16x8 bh0 = *(const bf16x8*)(Bh + bb);
      bf16x8 bh1 = *(const bf16x8*)(Bh + bb + 32);
      bf16x8 bl0 = *(const bf16x8*)(Bl + bb);
      bf16x8 bl1 = *(const bf16x8*)(Bl + bb + 32);
      #pragma unroll
      for (int s = 0; s < 2; ++s) {
        acc[c4][s] = mfma16(a_h[s][0], bh0, acc[c4][s]);
        acc[c4][s] = mfma16(a_h[s][1], bh1, acc[c4][s]);
        acc[c4][s] = mfma16(a_l[s][0], bh0, acc[c4][s]);
        acc[c4][s] = mfma16(a_l[s][1], bh1, acc[c4][s]);
        acc[c4][s] = mfma16(a_h[s][0], bl0, acc[c4][s]);
        acc[c4][s] = mfma16(a_h[s][1], bl1, acc[c4][s]);
      }
    }
    // ---- phase B: transform + one rescale per super-tile ----
    float hv[4];
    #pragma unroll
    for (int c4 = 0; c4 < 4; ++c4) hv[c4] = hp2[(st * 4 + c4) * 16 + mrow];
    #pragma unroll
    for (int s = 0; s < 2; ++s)
      #pragma unroll
      for (int q = 0; q < 4; ++q) {
        float t0 = fmaf(acc[0][s][q], k1, hv[0]);
        float t1 = fmaf(acc[1][s][q], k1, hv[1]);
        float t2 = fmaf(acc[2][s][q], k1, hv[2]);
        float t3 = fmaf(acc[3][s][q], k1, hv[3]);
        float loc = fmaxf(fmaxf(t0, t1), fmaxf(t2, t3));
        float mn = fmaxf(m[s][q], loc);
        float sc = __builtin_amdgcn_exp2f(m[s][q] - mn);
        float sum = __builtin_amdgcn_exp2f(t0 - mn) +
                    __builtin_amdgcn_exp2f(t1 - mn) +
                    __builtin_amdgcn_exp2f(t2 - mn) +
                    __builtin_amdgcn_exp2f(t3 - mn);
        sm[s][q] = fmaf(sm[s][q], sc, sum);
        m[s][q] = mn;
      }
  }

  // ---- cross-lane (16 mrow lanes) merge: max-reduce, single exp, sum ----
  #pragma unroll
  for (int s = 0; s < 2; ++s)
    #pragma unroll
    for (int q = 0; q < 4; ++q) {
      float mm = m[s][q];
      #pragma unroll
      for (int o = 1; o < 16; o <<= 1) mm = fmaxf(mm, __shfl_xor(mm, o, 64));
      float ss = sm[s][q] * __builtin_amdgcn_exp2f(m[s][q] - mm);
      #pragma unroll
      for (int o = 1; o < 16; o <<= 1) ss += __shfl_xor(ss, o, 64);
      if (mrow == 0) {
        int row = row0 + s * 16 + quad * 4 + q;
        part[((size_t)mat * NPTS + row) * 8 + blockIdx.x] = make_float2(mm, ss);
      }
    }
}

// ---------------------------------------------------------------------------
// Merge 8 colgrp partials per row (exp2 domain) -> softmin; fused update.
// ft = -eps*ln2*(m2 + log2(s)).  Grid 64 x 256 covers 4*NPTS rows.
// ---------------------------------------------------------------------------
__global__ __launch_bounds__(256) void merge_kernel(
    const float2* __restrict__ part,
    const float* __restrict__ potOld, float* __restrict__ potNew,
    float eps, int avg) {
  int r = blockIdx.x * 256 + threadIdx.x;
  const float4* p4 = (const float4*)(part + (size_t)r * 8);
  float4 a = p4[0], b = p4[1], c = p4[2], d = p4[3];
  float mv[8] = {a.x, a.z, b.x, b.z, c.x, c.z, d.x, d.z};
  float sv[8] = {a.y, a.w, b.y, b.w, c.y, c.w, d.y, d.w};
  float mm = mv[0];
  #pragma unroll
  for (int i = 1; i < 8; ++i) mm = fmaxf(mm, mv[i]);
  float ss = 0.0f;
  #pragma unroll
  for (int i = 0; i < 8; ++i)
    ss += sv[i] * __builtin_amdgcn_exp2f(mv[i] - mm);
  float ft = -eps * LN2 * (mm + __builtin_amdgcn_logf(ss));
  potNew[r] = avg ? 0.5f * (potOld[r] + ft) : ft;
}

// ---------------------------------------------------------------------------
// out = mean(f_ba - f_aa) + mean(g_ab - g_bb); pot layout [4][NPTS]
// ---------------------------------------------------------------------------
__global__ __launch_bounds__(256) void final_kernel(
    const float* __restrict__ pot, float* __restrict__ out) {
  __shared__ float red[256];
  float s = 0.0f;
  for (int j = threadIdx.x; j < NPTS; j += 256)
    s += (pot[j] - pot[2 * NPTS + j]) + (pot[NPTS + j] - pot[3 * NPTS + j]);
  red[threadIdx.x] = s;
  __syncthreads();
  #pragma unroll
  for (int o = 128; o; o >>= 1) {
    if (threadIdx.x < o) red[threadIdx.x] += red[threadIdx.x + o];
    __syncthreads();
  }
  if (threadIdx.x == 0) out[0] = red[0] / (float)NPTS;
}

extern "C" void kernel_launch(void* const* d_in, const int* in_sizes, int n_in,
                              void* d_out, int out_size, void* d_ws, size_t ws_size,
                              hipStream_t stream) {
  const float* x = (const float*)d_in[0];
  const float* y = (const float*)d_in[1];
  char* ws = (char*)d_ws;

  __bf16* xh = (__bf16*)ws;
  __bf16* xl = xh + (size_t)NPTS * DIM;
  __bf16* yh = xl + (size_t)NPTS * DIM;
  __bf16* yl = yh + (size_t)NPTS * DIM;
  float* potA = (float*)(yl + (size_t)NPTS * DIM);
  float* potB = potA + 4 * (size_t)NPTS;
  float2* part = (float2*)(potB + 4 * (size_t)NPTS);
  size_t needed = (size_t)((char*)(part + 4 * (size_t)NPTS * 8) - ws);
  if (ws_size < needed) return;

  norm_split_kernel<<<2048, 256, 0, stream>>>(x, y, xh, xl, yh, yl);

  // geomloss epsilon schedule (p=2, blur=0.05, scaling=0.8, diameter=2)
  double lst[32];
  int c = 0;
  lst[c++] = 4.0;
  double start = 2.0 * log(2.0), stop = 2.0 * log(0.05), step = 2.0 * log(0.8);
  for (int k = 0;; ++k) {
    double v = start + (double)k * step;
    if (v <= stop) break;
    lst[c++] = exp(v);
  }
  lst[c++] = 0.05 * 0.05;   // c == 19

  // sweeps: p=0 init (no pot, assign); p=1..c loop (avg); p=c+1 final (assign)
  for (int p = 0; p < c + 2; ++p) {
    double e = (p == 0) ? lst[0] : ((p <= c) ? lst[p - 1] : lst[c - 1]);
    float eps = (float)e;
    float inv_eps = 1.0f / eps;
    float k1 = inv_eps * LOG2E;
    float k0 = (LOGW - inv_eps) * LOG2E;
    int use_pot = (p > 0) ? 1 : 0;
    int avg = (p >= 1 && p <= c) ? 1 : 0;
    const float* po = (p & 1) ? potB : potA;
    float* pn       = (p & 1) ? potA : potB;
    pass_kernel<<<dim3(8, 32, 4), 256, 0, stream>>>(
        xh, xl, yh, yl, po, part, k1, k0, use_pot);
    merge_kernel<<<64, 256, 0, stream>>>(part, po, pn, (float)e, avg);
  }
  // 21 sweeps; last sweep (p=20, even) wrote potB
  final_kernel<<<1, 256, 0, stream>>>(potB, (float*)d_out);
}